// Round 7
// baseline (140.135 us; speedup 1.0000x reference)
//
#include <hip/hip_runtime.h>
#include <stdint.h>

#define Bn   8
#define CIN  64
#define Hh   128
#define Wh   128
#define COUT 64
#define Tt   9
#define HO   128
#define WO   128
#define HW   (HO * WO)

// R7: grid 512, 2 blocks/CU resident (single clean generation), 2 adjacent
// x-tiles per block. T14 async-stage: tile-B global loads issued before
// compute-A, ds_write after; B staging latency hides under A compute.
// Tile/region/swizzle frozen from R6:
//   8x16 px tile, region 17x24 recs, 128-B records, 3-bit unit XOR swizzle
//   write qs = quad ^ (rec&7); read byte = (rec<<7|g<<4)^((rec&7)<<4)^(ks<<5)
//   LDS 52,224 B single buffer.
#define RH     17
#define RWC    24
#define RREC   (RH * RWC)    // 408
#define HALO_Y 4
#define HALO_X 4

typedef _Float16 h16;
typedef __attribute__((ext_vector_type(2)))  _Float16 h2;
typedef __attribute__((ext_vector_type(8)))  _Float16 h8;
typedef __attribute__((ext_vector_type(16))) float    f16v;

// Module-scope scratch (NOT d_ws: R1 overflowed ws_size and corrupted the
// harness's pristine inputs). 16 MiB fp16 NHWC x + 72 KiB fp16 weights.
__device__ h16 g_xT[(size_t)Bn * Hh * Wh * CIN];
__device__ h16 g_wh[Tt * 4 * 2 * 64 * 8];   // [t][ks][mt][lane][j]

// ---------------------------------------------------------------------------
// prep: blocks [0,1024) transpose x NCHW fp32 -> g_xT NHWC fp16 (block per
// (b,y)); blocks [1024,1168) repack weight -> fp16 32x32x16 A-frag order:
// a(t,ks,mt)[lane][j] = W[o = mt*32 + (lane&31)][c = ks*16 + (lane>>5)*8 + j]
// ---------------------------------------------------------------------------
__global__ __launch_bounds__(256) void prep(const float* __restrict__ x,
                                            const float* __restrict__ w) {
    if (blockIdx.x >= Bn * Hh) {
        int tid = (blockIdx.x - Bn * Hh) * 256 + threadIdx.x;   // 36864
        int t   = tid >> 12;
        int rem = tid & 4095;
        int ks  = rem >> 10;
        int mt  = (rem >> 9) & 1;
        int ln  = (rem >> 3) & 63;
        int j   = rem & 7;
        int o   = mt * 32 + (ln & 31);
        int c   = ks * 16 + ((ln >> 5) << 3) + j;
        g_wh[tid] = (h16)w[(size_t)(o * 64 + c) * 9 + t];
        return;
    }
    int b = blockIdx.x >> 7;
    int y = blockIdx.x & 127;
    __shared__ uint32_t tile[64][65];   // [c][x/2] packed fp16 pair

    const float* src = x + ((size_t)b * CIN) * (Hh * Wh) + (size_t)y * Wh;
    int t    = threadIdx.x;
    int xp   = t & 63;     // x-pair
    int csub = t >> 6;     // 0..3
    #pragma unroll
    for (int cc = 0; cc < 64; cc += 4) {
        int c = cc + csub;
        float2 v = *(const float2*)(src + (size_t)c * (Hh * Wh) + xp * 2);
        uint32_t h0 = (uint32_t)__builtin_bit_cast(uint16_t, (h16)v.x);
        uint32_t h1 = (uint32_t)__builtin_bit_cast(uint16_t, (h16)v.y);
        tile[c][xp] = h0 | (h1 << 16);
    }
    __syncthreads();

    uint32_t* dst = (uint32_t*)(g_xT + (((size_t)b * Hh + y) * Wh) * CIN);
    int d  = t & 31;
    int xo = t >> 5;
    #pragma unroll
    for (int it = 0; it < 16; ++it) {
        int xg = it * 8 + xo;
        uint32_t lo = tile[2 * d][xg >> 1];
        uint32_t hi = tile[2 * d + 1][xg >> 1];
        int sh = (xg & 1) * 16;
        uint32_t l0 = (lo >> sh) & 0xffffu;
        uint32_t h1 = (hi >> sh) & 0xffffu;
        dst[xg * 32 + d] = l0 | (h1 << 16);
    }
}

// ---- helpers (all force-inlined; arrays touched only at unrolled const
// indices so they stay in registers) ----------------------------------------

__device__ __forceinline__ void stage_load(const h16* __restrict__ xb,
                                           int base_y, int base_x, int tid,
                                           uint4 sv[13]) {
    #pragma unroll
    for (int it = 0; it < 13; ++it) {
        int idx  = it * 256 + tid;
        int rec  = idx >> 3;
        int quad = idx & 7;
        if (rec < RREC) {
            int ry = rec / RWC, rx = rec - ry * RWC;
            int gy = min(max(base_y + ry, 0), Hh - 1);
            int gx = min(max(base_x + rx, 0), Wh - 1);
            sv[it] = *(const uint4*)(xb + ((gy << 7) + gx) * 64 + quad * 8);
        }
    }
}

__device__ __forceinline__ void stage_write(uint8_t* __restrict__ sreg,
                                            int tid, const uint4 sv[13]) {
    #pragma unroll
    for (int it = 0; it < 13; ++it) {
        int idx  = it * 256 + tid;
        int rec  = idx >> 3;
        int quad = idx & 7;
        if (rec < RREC) {
            int qs = quad ^ (rec & 7);
            *(uint4*)(sreg + rec * 128 + qs * 16) = sv[it];
        }
    }
}

__device__ __forceinline__ void load_offs(const float* __restrict__ offB,
                                          const float* __restrict__ mskB,
                                          int p, float dyv[Tt], float dxv[Tt],
                                          float mmv[Tt]) {
    #pragma unroll
    for (int t = 0; t < Tt; ++t) {
        dyv[t] = offB[(2 * t) * HW + p];
        dxv[t] = offB[(2 * t + 1) * HW + p];
        mmv[t] = mskB[t * HW + p];
    }
}

__device__ __forceinline__ void compute_tile(
        const uint8_t* __restrict__ sreg, const h16* __restrict__ xb,
        const float dyv[Tt], const float dxv[Tt], const float mmv[Tt],
        int i, int j, int p, int i0, int j0, int g, int lane,
        float* __restrict__ out, int b, const float* __restrict__ bias) {
    f16v acc[2] = {};

    #pragma unroll
    for (int t = 0; t < Tt; ++t) {
        const int ky = t / 3, kx = t % 3;
        float py = dyv[t] + (float)(i + ky - 1);
        float px = dxv[t] + (float)(j + kx - 1);
        float fy = floorf(py), fx = floorf(px);
        int   y0 = (int)fy,    x0 = (int)fx;
        float ly = py - fy,    lx = px - fx;
        float hy = 1.f - ly,   hx = 1.f - lx;

        bool vy0 = (y0 >= 0) && (y0 < Hh);
        bool vy1 = (y0 >= -1) && (y0 < Hh - 1);
        bool vx0 = (x0 >= 0) && (x0 < Wh);
        bool vx1 = (x0 >= -1) && (x0 < Wh - 1);
        float m = mmv[t];
        float w00 = (vy0 && vx0) ? hy * hx * m : 0.f;
        float w01 = (vy0 && vx1) ? hy * lx * m : 0.f;
        float w10 = (vy1 && vx0) ? ly * hx * m : 0.f;
        float w11 = (vy1 && vx1) ? ly * lx * m : 0.f;

        // region-local record coords; corner+1 needs ry<=RH-2, rx<=RWC-2
        int ry = y0 - i0 + HALO_Y;
        int rx = x0 - j0 + HALO_X;
        bool intile = (ry >= 0) & (ry <= RH - 2) & (rx >= 0) & (rx <= RWC - 2);
        int ryc = min(max(ry, 0), RH - 2), rxc = min(max(rx, 0), RWC - 2);
        int pl00 = ryc * RWC + rxc;
        int r00 = pl00, r01 = pl00 + 1, r10 = pl00 + RWC, r11 = pl00 + RWC + 1;
        // Swizzled per-record bases; per-ks read = base ^ (ks<<5).
        int q00 = ((r00 << 7) | (g << 4)) ^ ((r00 & 7) << 4);
        int q01 = ((r01 << 7) | (g << 4)) ^ ((r01 & 7) << 4);
        int q10 = ((r10 << 7) | (g << 4)) ^ ((r10 & 7) << 4);
        int q11 = ((r11 << 7) | (g << 4)) ^ ((r11 & 7) << 4);

        union U4 { uint4 v; h2 h[4]; };
        U4 c00[4], c01[4], c10[4], c11[4];
        #pragma unroll
        for (int ks = 0; ks < 4; ++ks) {
            c00[ks].v = *(const uint4*)(sreg + (q00 ^ (ks << 5)));
            c01[ks].v = *(const uint4*)(sreg + (q01 ^ (ks << 5)));
            c10[ks].v = *(const uint4*)(sreg + (q10 ^ (ks << 5)));
            c11[ks].v = *(const uint4*)(sreg + (q11 ^ (ks << 5)));
        }
        if (__any(!intile)) {   // few-lane global fallback (offset beyond halo)
            if (!intile) {
                int y0c = min(max(y0, 0), Hh - 1), y1c = min(max(y0 + 1, 0), Hh - 1);
                int x0c = min(max(x0, 0), Wh - 1), x1c = min(max(x0 + 1, 0), Wh - 1);
                const h16* r0p = xb + (size_t)(y0c * Wh) * CIN;
                const h16* r1p = xb + (size_t)(y1c * Wh) * CIN;
                #pragma unroll
                for (int ks = 0; ks < 4; ++ks) {
                    int c = ks * 16 + g * 8;
                    c00[ks].v = *(const uint4*)(r0p + x0c * CIN + c);
                    c01[ks].v = *(const uint4*)(r0p + x1c * CIN + c);
                    c10[ks].v = *(const uint4*)(r1p + x0c * CIN + c);
                    c11[ks].v = *(const uint4*)(r1p + x1c * CIN + c);
                }
            }
        }

        h2 W00 = {(h16)w00, (h16)w00};
        h2 W01 = {(h16)w01, (h16)w01};
        h2 W10 = {(h16)w10, (h16)w10};
        h2 W11 = {(h16)w11, (h16)w11};

        const h16* wt = g_wh + t * 4096;
        #pragma unroll
        for (int ks = 0; ks < 4; ++ks) {
            union { h2 r[4]; h8 v; } pk;
            #pragma unroll
            for (int e = 0; e < 4; ++e) {
                h2 r = c00[ks].h[e] * W00;
                r = c01[ks].h[e] * W01 + r;
                r = c10[ks].h[e] * W10 + r;
                r = c11[ks].h[e] * W11 + r;
                pk.r[e] = r;
            }
            #pragma unroll
            for (int mt = 0; mt < 2; ++mt) {
                h8 a = *(const h8*)(wt + (ks * 2 + mt) * 512 + lane * 8);
                acc[mt] = __builtin_amdgcn_mfma_f32_32x32x16_f16(
                    a, pk.v, acc[mt], 0, 0, 0);
            }
        }
    }

    // C/D layout (32x32): col = lane&31 (= px), row = (r&3) + 8*(r>>2) + 4*g.
    #pragma unroll
    for (int mt = 0; mt < 2; ++mt) {
        #pragma unroll
        for (int r = 0; r < 16; ++r) {
            int o = mt * 32 + (r & 3) + 8 * (r >> 2) + 4 * g;
            out[(size_t)(b * COUT + o) * HW + p] = acc[mt][r] + bias[o];
        }
    }
}

// ---------------------------------------------------------------------------
// dcn_main R7: 512 blocks x 4 waves, 2 adjacent x-tiles per block.
// stage A -> bar -> {issue B loads, B offsets} -> compute A -> bar ->
// ds_write B -> bar -> compute B. B's global latency hides under compute A.
// ---------------------------------------------------------------------------
__global__ __launch_bounds__(256, 2) void dcn_main(
        const float* __restrict__ offset, const float* __restrict__ mask,
        const float* __restrict__ bias, float* __restrict__ out) {
    __shared__ __align__(16) uint8_t sreg[RREC * 128];   // 52,224 B

    int blk  = blockIdx.x;           // 0..511
    int b    = blk & 7;              // XCD-affine batch
    int k    = blk >> 3;             // 0..63 pair id
    int ty   = k >> 2;               // 0..15
    int txp  = k & 3;                // 0..3
    int i0   = ty * 8;
    int j0A  = (txp * 2) * 16;
    int j0B  = j0A + 16;
    int tid  = threadIdx.x;
    int lane = tid & 63;
    int wave = tid >> 6;
    int n    = lane & 31;            // pixel within wave
    int g    = lane >> 5;            // channel group (8 ch)

    const h16* xb = g_xT + (size_t)b * (Hh * Wh * CIN);

    int i  = i0 + 2 * wave + (n >> 4);
    int jA = j0A + (n & 15);
    int pA = (i << 7) + jA;

    const float* offB = offset + (size_t)b * (2 * Tt * HW);
    const float* mskB = mask   + (size_t)b * (Tt * HW);

    // ---- tile A: offsets + stage ----
    float dyA[Tt], dxA[Tt], mmA[Tt];
    load_offs(offB, mskB, pA, dyA, dxA, mmA);

    uint4 sv[13];
    stage_load(xb, i0 - HALO_Y, j0A - HALO_X, tid, sv);
    stage_write(sreg, tid, sv);
    __syncthreads();

    // ---- issue tile-B global traffic early (hides under compute A) ----
    stage_load(xb, i0 - HALO_Y, j0B - HALO_X, tid, sv);
    float dyB[Tt], dxB[Tt], mmB[Tt];
    load_offs(offB, mskB, pA + 16, dyB, dxB, mmB);

    // ---- compute tile A ----
    compute_tile(sreg, xb, dyA, dxA, mmA, i, jA, pA, i0, j0A, g, lane,
                 out, b, bias);
    __syncthreads();            // all waves done reading buffer (tile A)

    stage_write(sreg, tid, sv); // compiler waits vmcnt for sv as needed
    __syncthreads();

    // ---- compute tile B ----
    compute_tile(sreg, xb, dyB, dxB, mmB, i, jA + 16, pA + 16, i0, j0B, g,
                 lane, out, b, bias);
}

extern "C" void kernel_launch(void* const* d_in, const int* in_sizes, int n_in,
                              void* d_out, int out_size, void* d_ws, size_t ws_size,
                              hipStream_t stream) {
    const float* x      = (const float*)d_in[0];
    const float* offset = (const float*)d_in[1];
    const float* mask   = (const float*)d_in[2];
    const float* weight = (const float*)d_in[3];
    const float* bias   = (const float*)d_in[4];
    (void)d_ws; (void)ws_size;

    prep<<<Bn * Hh + 144, 256, 0, stream>>>(x, weight);
    dcn_main<<<Bn * 64, 256, 0, stream>>>(offset, mask, bias, (float*)d_out);
}

// Round 8
// 121.467 us; speedup vs baseline: 1.1537x; 1.1537x over previous
//
#include <hip/hip_runtime.h>
#include <stdint.h>

#define Bn   8
#define CIN  64
#define Hh   128
#define Wh   128
#define COUT 64
#define Tt   9
#define HO   128
#define WO   128
#define HW   (HO * WO)

// Block tile = 8 rows x 16 cols of output pixels (128 px, 4 waves x 32 px,
// 32x32x16 MFMA). Staged region: 17 x 24 records (halo y:4/4, x:4/3 eff).
// R8 = R6 + global_load_lds staging (16B DMA, no VGPR round-trip):
//   LDS dest LINEAR: unit u = it*256+tid, slot s = u&7, byte = u*16
//   source pre-swizzled: slot s of record rec loads quad q = s ^ (rec&7)
//   read side unchanged from R6: slot = ((ks<<1)|g) ^ (rec&7)  (involution)
// R7 lesson: register-staged async (sv[13] through helpers) spilled to
// scratch (+78 MB HBM traffic). DMA staging avoids registers entirely.
// LDS = 52,224 B -> 3 blocks/CU.
#define RH     17
#define RWC    24
#define RREC   (RH * RWC)    // 408
#define HALO_Y 4
#define HALO_X 4

typedef _Float16 h16;
typedef __attribute__((ext_vector_type(2)))  _Float16 h2;
typedef __attribute__((ext_vector_type(8)))  _Float16 h8;
typedef __attribute__((ext_vector_type(16))) float    f16v;

// Module-scope scratch (NOT d_ws: R1 overflowed ws_size and corrupted the
// harness's pristine inputs). 16 MiB fp16 NHWC x + 72 KiB fp16 weights.
__device__ h16 g_xT[(size_t)Bn * Hh * Wh * CIN];
__device__ h16 g_wh[Tt * 4 * 2 * 64 * 8];   // [t][ks][mt][lane][j]

// ---------------------------------------------------------------------------
// prep: blocks [0,1024) transpose x NCHW fp32 -> g_xT NHWC fp16 (block per
// (b,y)); blocks [1024,1168) repack weight -> fp16 32x32x16 A-frag order:
// a(t,ks,mt)[lane][j] = W[o = mt*32 + (lane&31)][c = ks*16 + (lane>>5)*8 + j]
// ---------------------------------------------------------------------------
__global__ __launch_bounds__(256) void prep(const float* __restrict__ x,
                                            const float* __restrict__ w) {
    if (blockIdx.x >= Bn * Hh) {
        int tid = (blockIdx.x - Bn * Hh) * 256 + threadIdx.x;   // 36864
        int t   = tid >> 12;
        int rem = tid & 4095;
        int ks  = rem >> 10;
        int mt  = (rem >> 9) & 1;
        int ln  = (rem >> 3) & 63;
        int j   = rem & 7;
        int o   = mt * 32 + (ln & 31);
        int c   = ks * 16 + ((ln >> 5) << 3) + j;
        g_wh[tid] = (h16)w[(size_t)(o * 64 + c) * 9 + t];
        return;
    }
    int b = blockIdx.x >> 7;
    int y = blockIdx.x & 127;
    __shared__ uint32_t tile[64][65];   // [c][x/2] packed fp16 pair

    const float* src = x + ((size_t)b * CIN) * (Hh * Wh) + (size_t)y * Wh;
    int t    = threadIdx.x;
    int xp   = t & 63;     // x-pair
    int csub = t >> 6;     // 0..3
    #pragma unroll
    for (int cc = 0; cc < 64; cc += 4) {
        int c = cc + csub;
        float2 v = *(const float2*)(src + (size_t)c * (Hh * Wh) + xp * 2);
        uint32_t h0 = (uint32_t)__builtin_bit_cast(uint16_t, (h16)v.x);
        uint32_t h1 = (uint32_t)__builtin_bit_cast(uint16_t, (h16)v.y);
        tile[c][xp] = h0 | (h1 << 16);
    }
    __syncthreads();

    uint32_t* dst = (uint32_t*)(g_xT + (((size_t)b * Hh + y) * Wh) * CIN);
    int d  = t & 31;
    int xo = t >> 5;
    #pragma unroll
    for (int it = 0; it < 16; ++it) {
        int xg = it * 8 + xo;
        uint32_t lo = tile[2 * d][xg >> 1];
        uint32_t hi = tile[2 * d + 1][xg >> 1];
        int sh = (xg & 1) * 16;
        uint32_t l0 = (lo >> sh) & 0xffffu;
        uint32_t h1 = (hi >> sh) & 0xffffu;
        dst[xg * 32 + d] = l0 | (h1 << 16);
    }
}

// ---------------------------------------------------------------------------
// dcn_main: 1024 blocks x 4 waves; wave owns 2 rows x 16 cols (32 px) x all
// 64 COUT via 2x v_mfma_f32_32x32x16_f16 per (tap,ks). Region in LDS at
// 128-B records, 3-bit XOR swizzle (applied on the global SOURCE for the
// DMA staging, and on the read address). b = blk&7: XCD-affine L2.
// ---------------------------------------------------------------------------
__global__ __launch_bounds__(256, 3) void dcn_main(
        const float* __restrict__ offset, const float* __restrict__ mask,
        const float* __restrict__ bias, float* __restrict__ out) {
    __shared__ __align__(16) uint8_t sreg[RREC * 128];   // 52,224 B

    int blk  = blockIdx.x;
    int b    = blk & 7;
    int s    = blk >> 3;            // tile id within batch, 128 tiles
    int ty   = s >> 3, tx = s & 7;
    int i0   = ty * 8, j0 = tx * 16;
    int tid  = threadIdx.x;
    int lane = tid & 63;
    int wave = tid >> 6;
    int n    = lane & 31;           // pixel within wave
    int g    = lane >> 5;           // channel group (8 ch)

    const h16* xb = g_xT + (size_t)b * (Hh * Wh * CIN);

    int i = i0 + 2 * wave + (n >> 4);
    int j = j0 + (n & 15);
    int p = (i << 7) + j;

    // Hoisted: independent of staging, overlaps its latency.
    const float* offB = offset + (size_t)b * (2 * Tt * HW);
    const float* mskB = mask   + (size_t)b * (Tt * HW);
    float dyv[Tt], dxv[Tt], mmv[Tt];
    #pragma unroll
    for (int t = 0; t < Tt; ++t) {
        dyv[t] = offB[(2 * t) * HW + p];
        dxv[t] = offB[(2 * t + 1) * HW + p];
        mmv[t] = mskB[t * HW + p];
    }

    // ---- stage region via global_load_lds: 408 recs x 8 slots = 3264 units.
    // Linear LDS dest (wave-uniform base + lane*16); swizzle applied on the
    // per-lane SOURCE address: slot s gets quad q = s ^ (rec&7).
    {
        const int base_y = i0 - HALO_Y, base_x = j0 - HALO_X;
        #pragma unroll
        for (int it = 0; it < 13; ++it) {
            int u   = it * 256 + tid;       // global unit id
            int rec = u >> 3;
            if (rec < RREC) {
                int sl = u & 7;
                int ry = rec / RWC, rx = rec - ry * RWC;
                int gy = min(max(base_y + ry, 0), Hh - 1);
                int gx = min(max(base_x + rx, 0), Wh - 1);
                int q  = sl ^ (rec & 7);
                const h16* src = xb + ((gy << 7) + gx) * 64 + q * 8;
                __builtin_amdgcn_global_load_lds(
                    (const __attribute__((address_space(1))) uint32_t*)src,
                    (__attribute__((address_space(3))) uint32_t*)
                        (sreg + it * 4096 + wave * 1024),
                    16, 0, 0);
            }
        }
    }
    __syncthreads();   // compiler drains vmcnt before the barrier

    f16v acc[2] = {};

    #pragma unroll
    for (int t = 0; t < Tt; ++t) {
        const int ky = t / 3, kx = t % 3;
        float py = dyv[t] + (float)(i + ky - 1);
        float px = dxv[t] + (float)(j + kx - 1);
        float fy = floorf(py), fx = floorf(px);
        int   y0 = (int)fy,    x0 = (int)fx;
        float ly = py - fy,    lx = px - fx;
        float hy = 1.f - ly,   hx = 1.f - lx;

        bool vy0 = (y0 >= 0) && (y0 < Hh);
        bool vy1 = (y0 >= -1) && (y0 < Hh - 1);
        bool vx0 = (x0 >= 0) && (x0 < Wh);
        bool vx1 = (x0 >= -1) && (x0 < Wh - 1);
        float m = mmv[t];
        float w00 = (vy0 && vx0) ? hy * hx * m : 0.f;
        float w01 = (vy0 && vx1) ? hy * lx * m : 0.f;
        float w10 = (vy1 && vx0) ? ly * hx * m : 0.f;
        float w11 = (vy1 && vx1) ? ly * lx * m : 0.f;

        // region-local record coords; corner+1 needs ry<=RH-2, rx<=RWC-2
        int ry = y0 - i0 + HALO_Y;
        int rx = x0 - j0 + HALO_X;
        bool intile = (ry >= 0) & (ry <= RH - 2) & (rx >= 0) & (rx <= RWC - 2);
        int ryc = min(max(ry, 0), RH - 2), rxc = min(max(rx, 0), RWC - 2);
        int pl00 = ryc * RWC + rxc;
        int r00 = pl00, r01 = pl00 + 1, r10 = pl00 + RWC, r11 = pl00 + RWC + 1;
        // Swizzled per-record bases; per-ks read = base ^ (ks<<5).
        int q00 = ((r00 << 7) | (g << 4)) ^ ((r00 & 7) << 4);
        int q01 = ((r01 << 7) | (g << 4)) ^ ((r01 & 7) << 4);
        int q10 = ((r10 << 7) | (g << 4)) ^ ((r10 & 7) << 4);
        int q11 = ((r11 << 7) | (g << 4)) ^ ((r11 & 7) << 4);

        union U4 { uint4 v; h2 h[4]; };
        U4 c00[4], c01[4], c10[4], c11[4];
        #pragma unroll
        for (int ks = 0; ks < 4; ++ks) {
            c00[ks].v = *(const uint4*)(sreg + (q00 ^ (ks << 5)));
            c01[ks].v = *(const uint4*)(sreg + (q01 ^ (ks << 5)));
            c10[ks].v = *(const uint4*)(sreg + (q10 ^ (ks << 5)));
            c11[ks].v = *(const uint4*)(sreg + (q11 ^ (ks << 5)));
        }
        if (__any(!intile)) {   // few-lane global fallback (offset beyond halo)
            if (!intile) {
                int y0c = min(max(y0, 0), Hh - 1), y1c = min(max(y0 + 1, 0), Hh - 1);
                int x0c = min(max(x0, 0), Wh - 1), x1c = min(max(x0 + 1, 0), Wh - 1);
                const h16* r0p = xb + (size_t)(y0c * Wh) * CIN;
                const h16* r1p = xb + (size_t)(y1c * Wh) * CIN;
                #pragma unroll
                for (int ks = 0; ks < 4; ++ks) {
                    int c = ks * 16 + g * 8;
                    c00[ks].v = *(const uint4*)(r0p + x0c * CIN + c);
                    c01[ks].v = *(const uint4*)(r0p + x1c * CIN + c);
                    c10[ks].v = *(const uint4*)(r1p + x0c * CIN + c);
                    c11[ks].v = *(const uint4*)(r1p + x1c * CIN + c);
                }
            }
        }

        h2 W00 = {(h16)w00, (h16)w00};
        h2 W01 = {(h16)w01, (h16)w01};
        h2 W10 = {(h16)w10, (h16)w10};
        h2 W11 = {(h16)w11, (h16)w11};

        const h16* wt = g_wh + t * 4096;
        #pragma unroll
        for (int ks = 0; ks < 4; ++ks) {
            union { h2 r[4]; h8 v; } pk;
            #pragma unroll
            for (int e = 0; e < 4; ++e) {
                h2 r = c00[ks].h[e] * W00;
                r = c01[ks].h[e] * W01 + r;
                r = c10[ks].h[e] * W10 + r;
                r = c11[ks].h[e] * W11 + r;
                pk.r[e] = r;
            }
            #pragma unroll
            for (int mt = 0; mt < 2; ++mt) {
                h8 a = *(const h8*)(wt + (ks * 2 + mt) * 512 + lane * 8);
                acc[mt] = __builtin_amdgcn_mfma_f32_32x32x16_f16(
                    a, pk.v, acc[mt], 0, 0, 0);
            }
        }
    }

    // C/D layout (32x32): col = lane&31 (= px), row = (r&3) + 8*(r>>2) + 4*g.
    #pragma unroll
    for (int mt = 0; mt < 2; ++mt) {
        #pragma unroll
        for (int r = 0; r < 16; ++r) {
            int o = mt * 32 + (r & 3) + 8 * (r >> 2) + 4 * g;
            out[(size_t)(b * COUT + o) * HW + p] = acc[mt][r] + bias[o];
        }
    }
}

extern "C" void kernel_launch(void* const* d_in, const int* in_sizes, int n_in,
                              void* d_out, int out_size, void* d_ws, size_t ws_size,
                              hipStream_t stream) {
    const float* x      = (const float*)d_in[0];
    const float* offset = (const float*)d_in[1];
    const float* mask   = (const float*)d_in[2];
    const float* weight = (const float*)d_in[3];
    const float* bias   = (const float*)d_in[4];
    (void)d_ws; (void)ws_size;

    prep<<<Bn * Hh + 144, 256, 0, stream>>>(x, weight);
    dcn_main<<<Bn * 128, 256, 0, stream>>>(offset, mask, bias, (float*)d_out);
}

// Round 9
// 119.788 us; speedup vs baseline: 1.1699x; 1.0140x over previous
//
#include <hip/hip_runtime.h>
#include <stdint.h>

#define Bn   8
#define CIN  64
#define Hh   128
#define Wh   128
#define COUT 64
#define Tt   9
#define HO   128
#define WO   128
#define HW   (HO * WO)

// Block tile = 8 rows x 16 cols of output pixels (128 px, 4 waves x 32 px,
// 32x32x16 MFMA). Staged region: 17 x 24 records (halo y:4/4, x:4/3 eff).
// R9 = R8 + sched_barrier(0) after each tap's 16 corner ds_reads.
// R3 evidence: VGPR_Count=68 proves the compiler sinks ds_reads to their
// uses (4-read chunks) under launch_bounds(256,3) -- the same low-ILP
// schedule R3 measured as +14 us. The barrier pins all 16 reads in flight
// per tap (liveness ~64+misc VGPR, fits the ~170 cap at 3 waves/SIMD).
// Staging: global_load_lds DMA, linear LDS dest, source pre-swizzled:
//   slot s of record rec loads quad q = s ^ (rec&7)
//   read side: byte = (rec<<7|g<<4) ^ ((rec&7)<<4) ^ (ks<<5)
// LDS = 52,224 B -> 3 blocks/CU.
#define RH     17
#define RWC    24
#define RREC   (RH * RWC)    // 408
#define HALO_Y 4
#define HALO_X 4

typedef _Float16 h16;
typedef __attribute__((ext_vector_type(2)))  _Float16 h2;
typedef __attribute__((ext_vector_type(8)))  _Float16 h8;
typedef __attribute__((ext_vector_type(16))) float    f16v;

// Module-scope scratch (NOT d_ws: R1 overflowed ws_size and corrupted the
// harness's pristine inputs). 16 MiB fp16 NHWC x + 72 KiB fp16 weights.
__device__ h16 g_xT[(size_t)Bn * Hh * Wh * CIN];
__device__ h16 g_wh[Tt * 4 * 2 * 64 * 8];   // [t][ks][mt][lane][j]

// ---------------------------------------------------------------------------
// prep: blocks [0,1024) transpose x NCHW fp32 -> g_xT NHWC fp16 (block per
// (b,y)); blocks [1024,1168) repack weight -> fp16 32x32x16 A-frag order:
// a(t,ks,mt)[lane][j] = W[o = mt*32 + (lane&31)][c = ks*16 + (lane>>5)*8 + j]
// ---------------------------------------------------------------------------
__global__ __launch_bounds__(256) void prep(const float* __restrict__ x,
                                            const float* __restrict__ w) {
    if (blockIdx.x >= Bn * Hh) {
        int tid = (blockIdx.x - Bn * Hh) * 256 + threadIdx.x;   // 36864
        int t   = tid >> 12;
        int rem = tid & 4095;
        int ks  = rem >> 10;
        int mt  = (rem >> 9) & 1;
        int ln  = (rem >> 3) & 63;
        int j   = rem & 7;
        int o   = mt * 32 + (ln & 31);
        int c   = ks * 16 + ((ln >> 5) << 3) + j;
        g_wh[tid] = (h16)w[(size_t)(o * 64 + c) * 9 + t];
        return;
    }
    int b = blockIdx.x >> 7;
    int y = blockIdx.x & 127;
    __shared__ uint32_t tile[64][65];   // [c][x/2] packed fp16 pair

    const float* src = x + ((size_t)b * CIN) * (Hh * Wh) + (size_t)y * Wh;
    int t    = threadIdx.x;
    int xp   = t & 63;     // x-pair
    int csub = t >> 6;     // 0..3
    #pragma unroll
    for (int cc = 0; cc < 64; cc += 4) {
        int c = cc + csub;
        float2 v = *(const float2*)(src + (size_t)c * (Hh * Wh) + xp * 2);
        uint32_t h0 = (uint32_t)__builtin_bit_cast(uint16_t, (h16)v.x);
        uint32_t h1 = (uint32_t)__builtin_bit_cast(uint16_t, (h16)v.y);
        tile[c][xp] = h0 | (h1 << 16);
    }
    __syncthreads();

    uint32_t* dst = (uint32_t*)(g_xT + (((size_t)b * Hh + y) * Wh) * CIN);
    int d  = t & 31;
    int xo = t >> 5;
    #pragma unroll
    for (int it = 0; it < 16; ++it) {
        int xg = it * 8 + xo;
        uint32_t lo = tile[2 * d][xg >> 1];
        uint32_t hi = tile[2 * d + 1][xg >> 1];
        int sh = (xg & 1) * 16;
        uint32_t l0 = (lo >> sh) & 0xffffu;
        uint32_t h1 = (hi >> sh) & 0xffffu;
        dst[xg * 32 + d] = l0 | (h1 << 16);
    }
}

// ---------------------------------------------------------------------------
// dcn_main: 1024 blocks x 4 waves; wave owns 2 rows x 16 cols (32 px) x all
// 64 COUT via 2x v_mfma_f32_32x32x16_f16 per (tap,ks). Region in LDS at
// 128-B records, 3-bit XOR swizzle. b = blk&7: XCD-affine L2. 3 blocks/CU.
// ---------------------------------------------------------------------------
__global__ __launch_bounds__(256, 3) void dcn_main(
        const float* __restrict__ offset, const float* __restrict__ mask,
        const float* __restrict__ bias, float* __restrict__ out) {
    __shared__ __align__(16) uint8_t sreg[RREC * 128];   // 52,224 B

    int blk  = blockIdx.x;
    int b    = blk & 7;
    int s    = blk >> 3;            // tile id within batch, 128 tiles
    int ty   = s >> 3, tx = s & 7;
    int i0   = ty * 8, j0 = tx * 16;
    int tid  = threadIdx.x;
    int lane = tid & 63;
    int wave = tid >> 6;
    int n    = lane & 31;           // pixel within wave
    int g    = lane >> 5;           // channel group (8 ch)

    const h16* xb = g_xT + (size_t)b * (Hh * Wh * CIN);

    int i = i0 + 2 * wave + (n >> 4);
    int j = j0 + (n & 15);
    int p = (i << 7) + j;

    // Hoisted: independent of staging, overlaps its latency.
    const float* offB = offset + (size_t)b * (2 * Tt * HW);
    const float* mskB = mask   + (size_t)b * (Tt * HW);
    float dyv[Tt], dxv[Tt], mmv[Tt];
    #pragma unroll
    for (int t = 0; t < Tt; ++t) {
        dyv[t] = offB[(2 * t) * HW + p];
        dxv[t] = offB[(2 * t + 1) * HW + p];
        mmv[t] = mskB[t * HW + p];
    }

    // ---- stage region via global_load_lds: 408 recs x 8 slots = 3264 units.
    // Linear LDS dest (wave-uniform base + lane*16); swizzle applied on the
    // per-lane SOURCE address: slot s gets quad q = s ^ (rec&7).
    {
        const int base_y = i0 - HALO_Y, base_x = j0 - HALO_X;
        #pragma unroll
        for (int it = 0; it < 13; ++it) {
            int u   = it * 256 + tid;       // global unit id
            int rec = u >> 3;
            if (rec < RREC) {
                int sl = u & 7;
                int ry = rec / RWC, rx = rec - ry * RWC;
                int gy = min(max(base_y + ry, 0), Hh - 1);
                int gx = min(max(base_x + rx, 0), Wh - 1);
                int q  = sl ^ (rec & 7);
                const h16* src = xb + ((gy << 7) + gx) * 64 + q * 8;
                __builtin_amdgcn_global_load_lds(
                    (const __attribute__((address_space(1))) uint32_t*)src,
                    (__attribute__((address_space(3))) uint32_t*)
                        (sreg + it * 4096 + wave * 1024),
                    16, 0, 0);
            }
        }
    }
    __syncthreads();   // compiler drains vmcnt before the barrier

    f16v acc[2] = {};

    #pragma unroll
    for (int t = 0; t < Tt; ++t) {
        const int ky = t / 3, kx = t % 3;
        float py = dyv[t] + (float)(i + ky - 1);
        float px = dxv[t] + (float)(j + kx - 1);
        float fy = floorf(py), fx = floorf(px);
        int   y0 = (int)fy,    x0 = (int)fx;
        float ly = py - fy,    lx = px - fx;
        float hy = 1.f - ly,   hx = 1.f - lx;

        bool vy0 = (y0 >= 0) && (y0 < Hh);
        bool vy1 = (y0 >= -1) && (y0 < Hh - 1);
        bool vx0 = (x0 >= 0) && (x0 < Wh);
        bool vx1 = (x0 >= -1) && (x0 < Wh - 1);
        float m = mmv[t];
        float w00 = (vy0 && vx0) ? hy * hx * m : 0.f;
        float w01 = (vy0 && vx1) ? hy * lx * m : 0.f;
        float w10 = (vy1 && vx0) ? ly * hx * m : 0.f;
        float w11 = (vy1 && vx1) ? ly * lx * m : 0.f;

        // region-local record coords; corner+1 needs ry<=RH-2, rx<=RWC-2
        int ry = y0 - i0 + HALO_Y;
        int rx = x0 - j0 + HALO_X;
        bool intile = (ry >= 0) & (ry <= RH - 2) & (rx >= 0) & (rx <= RWC - 2);
        int ryc = min(max(ry, 0), RH - 2), rxc = min(max(rx, 0), RWC - 2);
        int pl00 = ryc * RWC + rxc;
        int r00 = pl00, r01 = pl00 + 1, r10 = pl00 + RWC, r11 = pl00 + RWC + 1;
        // Swizzled per-record bases; per-ks read = base ^ (ks<<5).
        int q00 = ((r00 << 7) | (g << 4)) ^ ((r00 & 7) << 4);
        int q01 = ((r01 << 7) | (g << 4)) ^ ((r01 & 7) << 4);
        int q10 = ((r10 << 7) | (g << 4)) ^ ((r10 & 7) << 4);
        int q11 = ((r11 << 7) | (g << 4)) ^ ((r11 & 7) << 4);

        union U4 { uint4 v; h2 h[4]; };
        U4 c00[4], c01[4], c10[4], c11[4];
        #pragma unroll
        for (int ks = 0; ks < 4; ++ks) {
            c00[ks].v = *(const uint4*)(sreg + (q00 ^ (ks << 5)));
            c01[ks].v = *(const uint4*)(sreg + (q01 ^ (ks << 5)));
            c10[ks].v = *(const uint4*)(sreg + (q10 ^ (ks << 5)));
            c11[ks].v = *(const uint4*)(sreg + (q11 ^ (ks << 5)));
        }
        if (__any(!intile)) {   // few-lane global fallback (offset beyond halo)
            if (!intile) {
                int y0c = min(max(y0, 0), Hh - 1), y1c = min(max(y0 + 1, 0), Hh - 1);
                int x0c = min(max(x0, 0), Wh - 1), x1c = min(max(x0 + 1, 0), Wh - 1);
                const h16* r0p = xb + (size_t)(y0c * Wh) * CIN;
                const h16* r1p = xb + (size_t)(y1c * Wh) * CIN;
                #pragma unroll
                for (int ks = 0; ks < 4; ++ks) {
                    int c = ks * 16 + g * 8;
                    c00[ks].v = *(const uint4*)(r0p + x0c * CIN + c);
                    c01[ks].v = *(const uint4*)(r0p + x1c * CIN + c);
                    c10[ks].v = *(const uint4*)(r1p + x0c * CIN + c);
                    c11[ks].v = *(const uint4*)(r1p + x1c * CIN + c);
                }
            }
        }
        // Pin schedule: keep all 16 corner reads issued here, in flight
        // together; forbid sinking them into the blend below (R3: sunk
        // 4-read chunks cost +14 us; R3's VGPR=68 proves the sink).
        __builtin_amdgcn_sched_barrier(0);

        h2 W00 = {(h16)w00, (h16)w00};
        h2 W01 = {(h16)w01, (h16)w01};
        h2 W10 = {(h16)w10, (h16)w10};
        h2 W11 = {(h16)w11, (h16)w11};

        const h16* wt = g_wh + t * 4096;
        #pragma unroll
        for (int ks = 0; ks < 4; ++ks) {
            union { h2 r[4]; h8 v; } pk;
            #pragma unroll
            for (int e = 0; e < 4; ++e) {
                h2 r = c00[ks].h[e] * W00;
                r = c01[ks].h[e] * W01 + r;
                r = c10[ks].h[e] * W10 + r;
                r = c11[ks].h[e] * W11 + r;
                pk.r[e] = r;
            }
            #pragma unroll
            for (int mt = 0; mt < 2; ++mt) {
                h8 a = *(const h8*)(wt + (ks * 2 + mt) * 512 + lane * 8);
                acc[mt] = __builtin_amdgcn_mfma_f32_32x32x16_f16(
                    a, pk.v, acc[mt], 0, 0, 0);
            }
        }
    }

    // C/D layout (32x32): col = lane&31 (= px), row = (r&3) + 8*(r>>2) + 4*g.
    #pragma unroll
    for (int mt = 0; mt < 2; ++mt) {
        #pragma unroll
        for (int r = 0; r < 16; ++r) {
            int o = mt * 32 + (r & 3) + 8 * (r >> 2) + 4 * g;
            out[(size_t)(b * COUT + o) * HW + p] = acc[mt][r] + bias[o];
        }
    }
}

extern "C" void kernel_launch(void* const* d_in, const int* in_sizes, int n_in,
                              void* d_out, int out_size, void* d_ws, size_t ws_size,
                              hipStream_t stream) {
    const float* x      = (const float*)d_in[0];
    const float* offset = (const float*)d_in[1];
    const float* mask   = (const float*)d_in[2];
    const float* weight = (const float*)d_in[3];
    const float* bias   = (const float*)d_in[4];
    (void)d_ws; (void)ws_size;

    prep<<<Bn * Hh + 144, 256, 0, stream>>>(x, weight);
    dcn_main<<<Bn * 128, 256, 0, stream>>>(offset, mask, bias, (float*)d_out);
}